// Round 1
// baseline (1478.353 us; speedup 1.0000x reference)
//
#include <hip/hip_runtime.h>
#include <cstdint>
#include <cstddef>

typedef __attribute__((ext_vector_type(4))) float fvec4;

#define NNODES 100000
#define NEDGES 1600000
#define INDIM  128
#define HC     128
#define NH     8
#define LEAKY  0.2f
#define SM_EPS 1e-16f
#define NB     32   // nodes per tile in k_gemm

// ---------------------------------------------------------------------------
// Kernel A: h = x @ W_lin  (+ per-node alpha_l, alpha_r),  resid = x @ W_res
// Block: 256 threads, tile = 32 nodes x 128 cols.
// LDS: W (64KB) + x tile (16KB) = 80KB exactly -> 2 blocks/CU.
// Thread (cq, nq): cq = tid&31 -> 4 consecutive cols, nq = tid>>5 -> 4 nodes.
// ---------------------------------------------------------------------------
__global__ __launch_bounds__(256) void k_gemm(
    const float* __restrict__ x,
    const float* __restrict__ W_lin,
    const float* __restrict__ W_res,
    const float* __restrict__ att_l,
    const float* __restrict__ att_r,
    float* __restrict__ h,
    float* __restrict__ alpha_l,
    float* __restrict__ alpha_r,
    float* __restrict__ resid)
{
    __shared__ float Ws[INDIM][HC];   // 64 KB
    __shared__ float xs[NB][INDIM];   // 16 KB

    const int tid    = threadIdx.x;
    const int n_base = blockIdx.x * NB;

    // load x tile (32*128 floats = 1024 fvec4)
    {
        const fvec4* src = (const fvec4*)(x + (size_t)n_base * INDIM);
        fvec4* dst = (fvec4*)&xs[0][0];
        #pragma unroll
        for (int i = 0; i < 4; ++i) dst[tid + 256 * i] = src[tid + 256 * i];
    }
    // load W_lin (16384 floats = 4096 fvec4)
    {
        const fvec4* src = (const fvec4*)W_lin;
        fvec4* dst = (fvec4*)&Ws[0][0];
        #pragma unroll
        for (int i = 0; i < 16; ++i) dst[tid + 256 * i] = src[tid + 256 * i];
    }
    __syncthreads();

    const int cq = tid & 31;
    const int nq = tid >> 5;
    const int c0 = cq * 4;
    const int n0 = nq * 4;

    fvec4 acc[4];

    auto mmtile = [&]() {
        #pragma unroll
        for (int i = 0; i < 4; ++i) { acc[i][0] = 0.f; acc[i][1] = 0.f; acc[i][2] = 0.f; acc[i][3] = 0.f; }
        #pragma unroll 4
        for (int k = 0; k < INDIM; k += 4) {
            fvec4 w0 = *(const fvec4*)&Ws[k + 0][c0];
            fvec4 w1 = *(const fvec4*)&Ws[k + 1][c0];
            fvec4 w2 = *(const fvec4*)&Ws[k + 2][c0];
            fvec4 w3 = *(const fvec4*)&Ws[k + 3][c0];
            #pragma unroll
            for (int i = 0; i < 4; ++i) {
                fvec4 xv = *(const fvec4*)&xs[n0 + i][k];
                acc[i] += xv[0] * w0;
                acc[i] += xv[1] * w1;
                acc[i] += xv[2] * w2;
                acc[i] += xv[3] * w3;
            }
        }
    };

    // ---- phase 1: h + alphas ----
    mmtile();
    #pragma unroll
    for (int i = 0; i < 4; ++i) {
        const int n = n_base + n0 + i;
        *(fvec4*)&h[(size_t)n * HC + c0] = acc[i];
    }
    // partial alpha over this thread's 4 cols (all within one head: c0 % 16 in {0,4,8,12})
    {
        float al0 = att_l[c0], al1 = att_l[c0 + 1], al2 = att_l[c0 + 2], al3 = att_l[c0 + 3];
        float ar0 = att_r[c0], ar1 = att_r[c0 + 1], ar2 = att_r[c0 + 2], ar3 = att_r[c0 + 3];
        float pl[4], pr[4];
        #pragma unroll
        for (int i = 0; i < 4; ++i) {
            pl[i] = acc[i][0] * al0 + acc[i][1] * al1 + acc[i][2] * al2 + acc[i][3] * al3;
            pr[i] = acc[i][0] * ar0 + acc[i][1] * ar1 + acc[i][2] * ar2 + acc[i][3] * ar3;
        }
        // reduce across the 4 adjacent lanes covering one head (cq groups of 4)
        #pragma unroll
        for (int i = 0; i < 4; ++i) {
            pl[i] += __shfl_xor(pl[i], 1); pl[i] += __shfl_xor(pl[i], 2);
            pr[i] += __shfl_xor(pr[i], 1); pr[i] += __shfl_xor(pr[i], 2);
        }
        if ((cq & 3) == 0) {
            const int head = cq >> 2;
            #pragma unroll
            for (int i = 0; i < 4; ++i) {
                const int n = n_base + n0 + i;
                alpha_l[(size_t)n * NH + head] = pl[i];
                alpha_r[(size_t)n * NH + head] = pr[i];
            }
        }
    }

    // ---- phase 2: resid = x @ W_res ----
    __syncthreads();
    {
        const fvec4* src = (const fvec4*)W_res;
        fvec4* dst = (fvec4*)&Ws[0][0];
        #pragma unroll
        for (int i = 0; i < 16; ++i) dst[tid + 256 * i] = src[tid + 256 * i];
    }
    __syncthreads();
    mmtile();
    #pragma unroll
    for (int i = 0; i < 4; ++i) {
        const int n = n_base + n0 + i;
        *(fvec4*)&resid[(size_t)n * HC + c0] = acc[i];
    }
}

// ---------------------------------------------------------------------------
// Kernel B: seg_sum[dst][h] += exp(leaky_relu(alpha_l[src][h] + alpha_r[dst][h]))
// (max-shift skipped: scores bounded ~|a|<6, exp safe; softmax ratio identical)
// ---------------------------------------------------------------------------
__global__ __launch_bounds__(256) void k_segsum(
    const int* __restrict__ ei,
    const float* __restrict__ alpha_l,
    const float* __restrict__ alpha_r,
    float* __restrict__ seg_sum)
{
    const int e = blockIdx.x * 256 + threadIdx.x;
    if (e >= NEDGES) return;
    const int src = ei[e];
    const int dst = ei[NEDGES + e];
    const fvec4* al = (const fvec4*)(alpha_l + (size_t)src * NH);
    const fvec4* ar = (const fvec4*)(alpha_r + (size_t)dst * NH);
    fvec4 a0 = al[0] + ar[0];
    fvec4 a1 = al[1] + ar[1];
    float* ss = seg_sum + (size_t)dst * NH;
    #pragma unroll
    for (int j = 0; j < 4; ++j) {
        float a = a0[j]; a = a > 0.f ? a : LEAKY * a;
        atomicAdd(&ss[j], __expf(a));
    }
    #pragma unroll
    for (int j = 0; j < 4; ++j) {
        float a = a1[j]; a = a > 0.f ? a : LEAKY * a;
        atomicAdd(&ss[4 + j], __expf(a));
    }
}

// ---------------------------------------------------------------------------
// Kernel C: agg[dst][:] += h[src][:] * coef[head]   (2 edges per 256-thr block)
// ---------------------------------------------------------------------------
__global__ __launch_bounds__(256) void k_msg(
    const int* __restrict__ ei,
    const float* __restrict__ alpha_l,
    const float* __restrict__ alpha_r,
    const float* __restrict__ seg_sum,
    const float* __restrict__ h,
    float* __restrict__ agg)
{
    const int e = blockIdx.x * 2 + (threadIdx.x >> 7);
    const int c = threadIdx.x & 127;
    if (e >= NEDGES) return;
    const int src  = ei[e];
    const int dst  = ei[NEDGES + e];
    const int head = c >> 4;
    float a = alpha_l[(size_t)src * NH + head] + alpha_r[(size_t)dst * NH + head];
    a = a > 0.f ? a : LEAKY * a;
    const float w = __expf(a);
    const float s = seg_sum[(size_t)dst * NH + head];
    const float coef = w / (s + SM_EPS);
    const float hv = h[(size_t)src * HC + c];
    atomicAdd(&agg[(size_t)dst * HC + c], hv * coef);
}

// ---------------------------------------------------------------------------
// Kernel D: out = elu(agg) + resid   (resid already in d_out)
// ---------------------------------------------------------------------------
__global__ __launch_bounds__(256) void k_final(
    const float* __restrict__ agg,
    float* __restrict__ out)
{
    const int i = blockIdx.x * 256 + threadIdx.x;  // fvec4 index; grid covers exactly
    fvec4 v = ((const fvec4*)agg)[i];
    fvec4 r = ((const fvec4*)out)[i];
    fvec4 o;
    #pragma unroll
    for (int j = 0; j < 4; ++j) {
        const float t = v[j];
        o[j] = t > 0.f ? t : expm1f(t);
    }
    ((fvec4*)out)[i] = o + r;
}

extern "C" void kernel_launch(void* const* d_in, const int* in_sizes, int n_in,
                              void* d_out, int out_size, void* d_ws, size_t ws_size,
                              hipStream_t stream)
{
    const float* x     = (const float*)d_in[0];
    const int*   ei    = (const int*)d_in[1];
    const float* W_lin = (const float*)d_in[2];
    const float* att_l = (const float*)d_in[3];
    const float* att_r = (const float*)d_in[4];
    const float* W_res = (const float*)d_in[5];
    float* out = (float*)d_out;

    // workspace layout (floats)
    float* h       = (float*)d_ws;                        // 12.8M
    float* agg     = h + (size_t)NNODES * HC;             // 12.8M
    float* seg_sum = agg + (size_t)NNODES * HC;           // 0.8M
    float* alpha_l = seg_sum + (size_t)NNODES * NH;       // 0.8M
    float* alpha_r = alpha_l + (size_t)NNODES * NH;       // 0.8M

    // zero agg + seg_sum every launch (ws is not re-poisoned between replays)
    hipMemsetAsync(agg, 0, ((size_t)NNODES * HC + (size_t)NNODES * NH) * sizeof(float), stream);

    k_gemm<<<NNODES / NB, 256, 0, stream>>>(x, W_lin, W_res, att_l, att_r,
                                            h, alpha_l, alpha_r, out);
    k_segsum<<<(NEDGES + 255) / 256, 256, 0, stream>>>(ei, alpha_l, alpha_r, seg_sum);
    k_msg<<<NEDGES / 2, 256, 0, stream>>>(ei, alpha_l, alpha_r, seg_sum, h, agg);
    k_final<<<(NNODES * HC / 4) / 256, 256, 0, stream>>>(agg, out);
}

// Round 2
// 754.137 us; speedup vs baseline: 1.9603x; 1.9603x over previous
//
#include <hip/hip_runtime.h>
#include <cstdint>
#include <cstddef>

typedef __attribute__((ext_vector_type(4))) float fvec4;
typedef __attribute__((ext_vector_type(2))) float fvec2;

#define NNODES 100000
#define NEDGES 1600000
#define INDIM  128
#define HC     128
#define NH     8
#define LEAKY  0.2f
#define SM_EPS 1e-16f
#define NB     32   // nodes per tile in k_gemm

// ---------------------------------------------------------------------------
// Kernel A: h = x @ W_lin  (+ per-node alpha_l, alpha_r),  resid = x @ W_res
// Block: 256 threads, tile = 32 nodes x 128 cols. LDS 80KB -> 2 blocks/CU.
// ---------------------------------------------------------------------------
__global__ __launch_bounds__(256) void k_gemm(
    const float* __restrict__ x,
    const float* __restrict__ W_lin,
    const float* __restrict__ W_res,
    const float* __restrict__ att_l,
    const float* __restrict__ att_r,
    float* __restrict__ h,
    float* __restrict__ alpha_l,
    float* __restrict__ alpha_r,
    float* __restrict__ resid)
{
    __shared__ float Ws[INDIM][HC];   // 64 KB
    __shared__ float xs[NB][INDIM];   // 16 KB

    const int tid    = threadIdx.x;
    const int n_base = blockIdx.x * NB;

    {
        const fvec4* src = (const fvec4*)(x + (size_t)n_base * INDIM);
        fvec4* dst = (fvec4*)&xs[0][0];
        #pragma unroll
        for (int i = 0; i < 4; ++i) dst[tid + 256 * i] = src[tid + 256 * i];
    }
    {
        const fvec4* src = (const fvec4*)W_lin;
        fvec4* dst = (fvec4*)&Ws[0][0];
        #pragma unroll
        for (int i = 0; i < 16; ++i) dst[tid + 256 * i] = src[tid + 256 * i];
    }
    __syncthreads();

    const int cq = tid & 31;
    const int nq = tid >> 5;
    const int c0 = cq * 4;
    const int n0 = nq * 4;

    fvec4 acc[4];

    auto mmtile = [&]() {
        #pragma unroll
        for (int i = 0; i < 4; ++i) { acc[i][0] = 0.f; acc[i][1] = 0.f; acc[i][2] = 0.f; acc[i][3] = 0.f; }
        #pragma unroll 4
        for (int k = 0; k < INDIM; k += 4) {
            fvec4 w0 = *(const fvec4*)&Ws[k + 0][c0];
            fvec4 w1 = *(const fvec4*)&Ws[k + 1][c0];
            fvec4 w2 = *(const fvec4*)&Ws[k + 2][c0];
            fvec4 w3 = *(const fvec4*)&Ws[k + 3][c0];
            #pragma unroll
            for (int i = 0; i < 4; ++i) {
                fvec4 xv = *(const fvec4*)&xs[n0 + i][k];
                acc[i] += xv[0] * w0;
                acc[i] += xv[1] * w1;
                acc[i] += xv[2] * w2;
                acc[i] += xv[3] * w3;
            }
        }
    };

    // ---- phase 1: h + alphas ----
    mmtile();
    #pragma unroll
    for (int i = 0; i < 4; ++i) {
        const int n = n_base + n0 + i;
        *(fvec4*)&h[(size_t)n * HC + c0] = acc[i];
    }
    {
        float al0 = att_l[c0], al1 = att_l[c0 + 1], al2 = att_l[c0 + 2], al3 = att_l[c0 + 3];
        float ar0 = att_r[c0], ar1 = att_r[c0 + 1], ar2 = att_r[c0 + 2], ar3 = att_r[c0 + 3];
        float pl[4], pr[4];
        #pragma unroll
        for (int i = 0; i < 4; ++i) {
            pl[i] = acc[i][0] * al0 + acc[i][1] * al1 + acc[i][2] * al2 + acc[i][3] * al3;
            pr[i] = acc[i][0] * ar0 + acc[i][1] * ar1 + acc[i][2] * ar2 + acc[i][3] * ar3;
        }
        #pragma unroll
        for (int i = 0; i < 4; ++i) {
            pl[i] += __shfl_xor(pl[i], 1); pl[i] += __shfl_xor(pl[i], 2);
            pr[i] += __shfl_xor(pr[i], 1); pr[i] += __shfl_xor(pr[i], 2);
        }
        if ((cq & 3) == 0) {
            const int head = cq >> 2;
            #pragma unroll
            for (int i = 0; i < 4; ++i) {
                const int n = n_base + n0 + i;
                alpha_l[(size_t)n * NH + head] = pl[i];
                alpha_r[(size_t)n * NH + head] = pr[i];
            }
        }
    }

    // ---- phase 2: resid = x @ W_res ----
    __syncthreads();
    {
        const fvec4* src = (const fvec4*)W_res;
        fvec4* dst = (fvec4*)&Ws[0][0];
        #pragma unroll
        for (int i = 0; i < 16; ++i) dst[tid + 256 * i] = src[tid + 256 * i];
    }
    __syncthreads();
    mmtile();
    #pragma unroll
    for (int i = 0; i < 4; ++i) {
        const int n = n_base + n0 + i;
        *(fvec4*)&resid[(size_t)n * HC + c0] = acc[i];
    }
}

// ---------------------------------------------------------------------------
// CSR build: histogram -> scan -> scatter (counting sort by dst)
// ---------------------------------------------------------------------------
__global__ __launch_bounds__(256) void k_hist(const int* __restrict__ ei,
                                              int* __restrict__ deg)
{
    const int e = blockIdx.x * 256 + threadIdx.x;
    if (e >= NEDGES) return;
    atomicAdd(&deg[ei[NEDGES + e]], 1);
}

__global__ __launch_bounds__(1024) void k_scan(const int* __restrict__ deg,
                                               int* __restrict__ row_start)
{
    __shared__ int part[1024];
    const int t = threadIdx.x;
    const int lo = t * 98;
    const int hi = min(lo + 98, NNODES);
    int s = 0;
    for (int i = lo; i < hi; ++i) s += deg[i];
    part[t] = s;
    __syncthreads();
    // Hillis-Steele inclusive scan
    for (int off = 1; off < 1024; off <<= 1) {
        int v = (t >= off) ? part[t - off] : 0;
        __syncthreads();
        part[t] += v;
        __syncthreads();
    }
    int base = part[t] - s;  // exclusive prefix
    for (int i = lo; i < hi; ++i) { row_start[i] = base; base += deg[i]; }
    if (t == 1023) row_start[NNODES] = part[1023];
}

__global__ __launch_bounds__(256) void k_scatter(const int* __restrict__ ei,
                                                 const int* __restrict__ row_start,
                                                 int* __restrict__ cursor,
                                                 int* __restrict__ csr_src)
{
    const int e = blockIdx.x * 256 + threadIdx.x;
    if (e >= NEDGES) return;
    const int src = ei[e];
    const int dst = ei[NEDGES + e];
    const int pos = row_start[dst] + atomicAdd(&cursor[dst], 1);
    csr_src[pos] = src;
}

// ---------------------------------------------------------------------------
// Kernel C: one wave per dst node. Pass 1: softmax denom per head (registers).
// Pass 2: gather h[src], accumulate 128 channels in regs, ELU + residual, one
// coalesced write. No atomics anywhere.
// Lane l owns channels {2l, 2l+1}; head(l) = l>>3.
// ---------------------------------------------------------------------------
__global__ __launch_bounds__(256) void k_msg(
    const int* __restrict__ row_start,
    const int* __restrict__ csr_src,
    const float* __restrict__ alpha_l,
    const float* __restrict__ alpha_r,
    const float* __restrict__ h,
    float* __restrict__ out)   // contains resid on entry
{
    const int n = blockIdx.x * 4 + (threadIdx.x >> 6);
    if (n >= NNODES) return;
    const int lane = threadIdx.x & 63;
    const int beg = row_start[n];
    const int end = row_start[n + 1];

    // pass 1: per-head exp-sum (head = lane&7, replicated 8x across wave)
    const int h1 = lane & 7;
    const float ar1 = alpha_r[(size_t)n * NH + h1];
    float ssum = 0.f;
    for (int p = beg; p < end; ++p) {
        const int src = csr_src[p];
        float a = alpha_l[(size_t)src * NH + h1] + ar1;
        a = a > 0.f ? a : LEAKY * a;
        ssum += __expf(a);
    }

    // lane's channels live in head = lane>>3; that head's sum sits at lane (lane>>3)
    const int hd = lane >> 3;
    const float inv = 1.f / (__shfl(ssum, hd) + SM_EPS);
    const float ar2 = alpha_r[(size_t)n * NH + hd];

    float acc0 = 0.f, acc1 = 0.f;
    for (int p = beg; p < end; ++p) {
        const int src = csr_src[p];
        float a = alpha_l[(size_t)src * NH + hd] + ar2;
        a = a > 0.f ? a : LEAKY * a;
        const float coef = __expf(a) * inv;
        const fvec2 hv = *(const fvec2*)&h[(size_t)src * HC + 2 * lane];
        acc0 += hv[0] * coef;
        acc1 += hv[1] * coef;
    }

    const fvec2 r = *(const fvec2*)&out[(size_t)n * HC + 2 * lane];
    fvec2 o;
    o[0] = (acc0 > 0.f ? acc0 : expm1f(acc0)) + r[0];
    o[1] = (acc1 > 0.f ? acc1 : expm1f(acc1)) + r[1];
    *(fvec2*)&out[(size_t)n * HC + 2 * lane] = o;
}

extern "C" void kernel_launch(void* const* d_in, const int* in_sizes, int n_in,
                              void* d_out, int out_size, void* d_ws, size_t ws_size,
                              hipStream_t stream)
{
    const float* x     = (const float*)d_in[0];
    const int*   ei    = (const int*)d_in[1];
    const float* W_lin = (const float*)d_in[2];
    const float* att_l = (const float*)d_in[3];
    const float* att_r = (const float*)d_in[4];
    const float* W_res = (const float*)d_in[5];
    float* out = (float*)d_out;

    // workspace layout
    float* h        = (float*)d_ws;                       // 12.8M floats
    float* alpha_l  = h + (size_t)NNODES * HC;            // 800k
    float* alpha_r  = alpha_l + (size_t)NNODES * NH;      // 800k
    int*   deg      = (int*)(alpha_r + (size_t)NNODES * NH);  // N
    int*   cursor   = deg + NNODES;                       // N
    int*   row_start= cursor + NNODES;                    // N+1
    int*   csr_src  = row_start + NNODES + 1;             // E

    // zero deg + cursor (adjacent) every launch
    hipMemsetAsync(deg, 0, 2 * (size_t)NNODES * sizeof(int), stream);

    k_gemm<<<NNODES / NB, 256, 0, stream>>>(x, W_lin, W_res, att_l, att_r,
                                            h, alpha_l, alpha_r, out);
    k_hist<<<(NEDGES + 255) / 256, 256, 0, stream>>>(ei, deg);
    k_scan<<<1, 1024, 0, stream>>>(deg, row_start);
    k_scatter<<<(NEDGES + 255) / 256, 256, 0, stream>>>(ei, row_start, cursor, csr_src);
    k_msg<<<(NNODES + 3) / 4, 256, 0, stream>>>(row_start, csr_src, alpha_l, alpha_r, h, out);
}

// Round 3
// 507.852 us; speedup vs baseline: 2.9110x; 1.4850x over previous
//
#include <hip/hip_runtime.h>
#include <cstdint>
#include <cstddef>

typedef __attribute__((ext_vector_type(4))) float fvec4;
typedef __attribute__((ext_vector_type(2))) float fvec2;
typedef __attribute__((ext_vector_type(4))) unsigned short usvec4;

#define NNODES 100000
#define NEDGES 1600000
#define INDIM  128
#define HC     128
#define NH     8
#define LEAKY  0.2f
#define SM_EPS 1e-16f
#define NB     32   // nodes per tile in k_gemm

__device__ __forceinline__ unsigned short f2bf_rne(float f) {
    uint32_t u = __builtin_bit_cast(uint32_t, f);
    u += 0x7FFFu + ((u >> 16) & 1u);
    return (unsigned short)(u >> 16);
}

// ---------------------------------------------------------------------------
// Kernel A: h(bf16) = x @ W_lin (+ alpha_l, alpha_r), resid = x @ W_res,
//           plus fused dst-degree histogram (512 edges per block).
// Block: 256 threads, tile = 32 nodes x 128 cols. LDS 80KB -> 2 blocks/CU.
// ---------------------------------------------------------------------------
__global__ __launch_bounds__(256) void k_gemm(
    const float* __restrict__ x,
    const float* __restrict__ W_lin,
    const float* __restrict__ W_res,
    const float* __restrict__ att_l,
    const float* __restrict__ att_r,
    const int*   __restrict__ ei,
    unsigned short* __restrict__ h16,
    float* __restrict__ alpha_l,
    float* __restrict__ alpha_r,
    float* __restrict__ resid,
    int*   __restrict__ deg)
{
    __shared__ float Ws[INDIM][HC];   // 64 KB
    __shared__ float xs[NB][INDIM];   // 16 KB

    const int tid    = threadIdx.x;
    const int n_base = blockIdx.x * NB;

    // fused histogram: 512 edges per block (3125 * 512 = 1.6M exactly)
    {
        const int e0 = blockIdx.x * 512 + tid;
        const int d0 = ei[NEDGES + e0];
        const int d1 = ei[NEDGES + e0 + 256];
        atomicAdd(&deg[d0], 1);
        atomicAdd(&deg[d1], 1);
    }

    {
        const fvec4* src = (const fvec4*)(x + (size_t)n_base * INDIM);
        fvec4* dst = (fvec4*)&xs[0][0];
        #pragma unroll
        for (int i = 0; i < 4; ++i) dst[tid + 256 * i] = src[tid + 256 * i];
    }
    {
        const fvec4* src = (const fvec4*)W_lin;
        fvec4* dst = (fvec4*)&Ws[0][0];
        #pragma unroll
        for (int i = 0; i < 16; ++i) dst[tid + 256 * i] = src[tid + 256 * i];
    }
    __syncthreads();

    const int cq = tid & 31;
    const int nq = tid >> 5;
    const int c0 = cq * 4;
    const int n0 = nq * 4;

    fvec4 acc[4];

    auto mmtile = [&]() {
        #pragma unroll
        for (int i = 0; i < 4; ++i) { acc[i][0] = 0.f; acc[i][1] = 0.f; acc[i][2] = 0.f; acc[i][3] = 0.f; }
        #pragma unroll 4
        for (int k = 0; k < INDIM; k += 4) {
            fvec4 w0 = *(const fvec4*)&Ws[k + 0][c0];
            fvec4 w1 = *(const fvec4*)&Ws[k + 1][c0];
            fvec4 w2 = *(const fvec4*)&Ws[k + 2][c0];
            fvec4 w3 = *(const fvec4*)&Ws[k + 3][c0];
            #pragma unroll
            for (int i = 0; i < 4; ++i) {
                fvec4 xv = *(const fvec4*)&xs[n0 + i][k];
                acc[i] += xv[0] * w0;
                acc[i] += xv[1] * w1;
                acc[i] += xv[2] * w2;
                acc[i] += xv[3] * w3;
            }
        }
    };

    // ---- phase 1: h (bf16) + alphas ----
    mmtile();
    #pragma unroll
    for (int i = 0; i < 4; ++i) {
        const int n = n_base + n0 + i;
        usvec4 hb;
        #pragma unroll
        for (int j = 0; j < 4; ++j) hb[j] = f2bf_rne(acc[i][j]);
        *(usvec4*)&h16[(size_t)n * HC + c0] = hb;
    }
    {
        float al0 = att_l[c0], al1 = att_l[c0 + 1], al2 = att_l[c0 + 2], al3 = att_l[c0 + 3];
        float ar0 = att_r[c0], ar1 = att_r[c0 + 1], ar2 = att_r[c0 + 2], ar3 = att_r[c0 + 3];
        float pl[4], pr[4];
        #pragma unroll
        for (int i = 0; i < 4; ++i) {
            pl[i] = acc[i][0] * al0 + acc[i][1] * al1 + acc[i][2] * al2 + acc[i][3] * al3;
            pr[i] = acc[i][0] * ar0 + acc[i][1] * ar1 + acc[i][2] * ar2 + acc[i][3] * ar3;
        }
        #pragma unroll
        for (int i = 0; i < 4; ++i) {
            pl[i] += __shfl_xor(pl[i], 1); pl[i] += __shfl_xor(pl[i], 2);
            pr[i] += __shfl_xor(pr[i], 1); pr[i] += __shfl_xor(pr[i], 2);
        }
        if ((cq & 3) == 0) {
            const int head = cq >> 2;
            #pragma unroll
            for (int i = 0; i < 4; ++i) {
                const int n = n_base + n0 + i;
                alpha_l[(size_t)n * NH + head] = pl[i];
                alpha_r[(size_t)n * NH + head] = pr[i];
            }
        }
    }

    // ---- phase 2: resid = x @ W_res ----
    __syncthreads();
    {
        const fvec4* src = (const fvec4*)W_res;
        fvec4* dst = (fvec4*)&Ws[0][0];
        #pragma unroll
        for (int i = 0; i < 16; ++i) dst[tid + 256 * i] = src[tid + 256 * i];
    }
    __syncthreads();
    mmtile();
    #pragma unroll
    for (int i = 0; i < 4; ++i) {
        const int n = n_base + n0 + i;
        *(fvec4*)&resid[(size_t)n * HC + c0] = acc[i];
    }
}

// ---------------------------------------------------------------------------
// CSR build: scan + scatter (counting sort by dst; hist fused into k_gemm)
// ---------------------------------------------------------------------------
__global__ __launch_bounds__(1024) void k_scan(const int* __restrict__ deg,
                                               int* __restrict__ row_start)
{
    __shared__ int part[1024];
    const int t = threadIdx.x;
    const int lo = t * 98;
    const int hi = min(lo + 98, NNODES);
    int s = 0;
    for (int i = lo; i < hi; ++i) s += deg[i];
    part[t] = s;
    __syncthreads();
    for (int off = 1; off < 1024; off <<= 1) {
        int v = (t >= off) ? part[t - off] : 0;
        __syncthreads();
        part[t] += v;
        __syncthreads();
    }
    int base = part[t] - s;  // exclusive prefix
    for (int i = lo; i < hi; ++i) { row_start[i] = base; base += deg[i]; }
    if (t == 1023) row_start[NNODES] = part[1023];
}

__global__ __launch_bounds__(256) void k_scatter(const int* __restrict__ ei,
                                                 const int* __restrict__ row_start,
                                                 int* __restrict__ cursor,
                                                 int* __restrict__ csr_src)
{
    const int e = blockIdx.x * 256 + threadIdx.x;
    if (e >= NEDGES) return;
    const int src = ei[e];
    const int dst = ei[NEDGES + e];
    const int pos = row_start[dst] + atomicAdd(&cursor[dst], 1);
    csr_src[pos] = src;
}

// ---------------------------------------------------------------------------
// Kernel C: one wave per dst node, SINGLE pass:
//   acc += w * h[src],  ssum += w,  w = exp(leaky(alpha_l[src]+alpha_r[n]))
// then out = elu(acc/ssum) + resid (resid already in d_out). No atomics.
// Lane l owns channels {2l, 2l+1}; head = l>>3.
// ---------------------------------------------------------------------------
__global__ __launch_bounds__(256) void k_msg(
    const int* __restrict__ row_start,
    const int* __restrict__ csr_src,
    const float* __restrict__ alpha_l,
    const float* __restrict__ alpha_r,
    const unsigned short* __restrict__ h16,
    float* __restrict__ out)
{
    const int n = blockIdx.x * 4 + (threadIdx.x >> 6);
    if (n >= NNODES) return;
    const int lane = threadIdx.x & 63;
    const int beg = row_start[n];
    const int end = row_start[n + 1];

    const int hd = lane >> 3;
    const float ar = alpha_r[(size_t)n * NH + hd];

    float ssum = 0.f, acc0 = 0.f, acc1 = 0.f;
    int src_n = (beg < end) ? csr_src[beg] : 0;
    for (int p = beg; p < end; ++p) {
        const int src = src_n;
        if (p + 1 < end) src_n = csr_src[p + 1];
        float a = alpha_l[(size_t)src * NH + hd] + ar;
        a = a > 0.f ? a : LEAKY * a;
        const float w = __expf(a);
        const uint32_t hv = *(const uint32_t*)&h16[(size_t)src * HC + 2 * lane];
        ssum += w;
        acc0 += w * __builtin_bit_cast(float, (hv & 0xFFFFu) << 16);
        acc1 += w * __builtin_bit_cast(float, hv & 0xFFFF0000u);
    }

    const float inv = 1.f / (ssum + SM_EPS);
    const float a0 = acc0 * inv;
    const float a1 = acc1 * inv;

    const fvec2 r = *(const fvec2*)&out[(size_t)n * HC + 2 * lane];
    fvec2 o;
    o[0] = (a0 > 0.f ? a0 : expm1f(a0)) + r[0];
    o[1] = (a1 > 0.f ? a1 : expm1f(a1)) + r[1];
    *(fvec2*)&out[(size_t)n * HC + 2 * lane] = o;
}

extern "C" void kernel_launch(void* const* d_in, const int* in_sizes, int n_in,
                              void* d_out, int out_size, void* d_ws, size_t ws_size,
                              hipStream_t stream)
{
    const float* x     = (const float*)d_in[0];
    const int*   ei    = (const int*)d_in[1];
    const float* W_lin = (const float*)d_in[2];
    const float* att_l = (const float*)d_in[3];
    const float* att_r = (const float*)d_in[4];
    const float* W_res = (const float*)d_in[5];
    float* out = (float*)d_out;

    // workspace layout
    unsigned short* h16 = (unsigned short*)d_ws;              // N*128 ushorts
    float* alpha_l  = (float*)(h16 + (size_t)NNODES * HC);    // N*8
    float* alpha_r  = alpha_l + (size_t)NNODES * NH;          // N*8
    int*   deg      = (int*)(alpha_r + (size_t)NNODES * NH);  // N
    int*   cursor   = deg + NNODES;                           // N
    int*   row_start= cursor + NNODES;                        // N+1
    int*   csr_src  = row_start + NNODES + 1;                 // E

    // zero deg + cursor (adjacent) every launch
    hipMemsetAsync(deg, 0, 2 * (size_t)NNODES * sizeof(int), stream);

    k_gemm<<<NNODES / NB, 256, 0, stream>>>(x, W_lin, W_res, att_l, att_r, ei,
                                            h16, alpha_l, alpha_r, out, deg);
    k_scan<<<1, 1024, 0, stream>>>(deg, row_start);
    k_scatter<<<(NEDGES + 255) / 256, 256, 0, stream>>>(ei, row_start, cursor, csr_src);
    k_msg<<<(NNODES + 3) / 4, 256, 0, stream>>>(row_start, csr_src, alpha_l, alpha_r, h16, out);
}

// Round 4
// 344.326 us; speedup vs baseline: 4.2935x; 1.4749x over previous
//
#include <hip/hip_runtime.h>
#include <cstdint>
#include <cstddef>

typedef __attribute__((ext_vector_type(4))) float fvec4;
typedef __attribute__((ext_vector_type(2))) float fvec2;
typedef __attribute__((ext_vector_type(4))) unsigned short usvec4;

#define NNODES 100000
#define NEDGES 1600000
#define INDIM  128
#define HC     128
#define NH     8
#define LEAKY  0.2f
#define SM_EPS 1e-16f
#define NB     32    // nodes per tile in k_gemm
#define NPART  98    // ceil(100000/1024)

__device__ __forceinline__ unsigned short f2bf_rne(float f) {
    uint32_t u = __builtin_bit_cast(uint32_t, f);
    u += 0x7FFFu + ((u >> 16) & 1u);
    return (unsigned short)(u >> 16);
}

// ---------------------------------------------------------------------------
// Kernel A: h(bf16) = x @ W_lin (+ alpha_l, alpha_r), resid = x @ W_res,
//           plus fused dst-degree histogram (512 edges per block).
// Block: 256 threads, tile = 32 nodes x 128 cols. LDS 80KB -> 2 blocks/CU.
// ---------------------------------------------------------------------------
__global__ __launch_bounds__(256) void k_gemm(
    const float* __restrict__ x,
    const float* __restrict__ W_lin,
    const float* __restrict__ W_res,
    const float* __restrict__ att_l,
    const float* __restrict__ att_r,
    const int*   __restrict__ ei,
    unsigned short* __restrict__ h16,
    float* __restrict__ alpha_l,
    float* __restrict__ alpha_r,
    float* __restrict__ resid,
    int*   __restrict__ deg)
{
    __shared__ float Ws[INDIM][HC];   // 64 KB
    __shared__ float xs[NB][INDIM];   // 16 KB

    const int tid    = threadIdx.x;
    const int n_base = blockIdx.x * NB;

    // fused histogram: 512 edges per block (3125 * 512 = 1.6M exactly)
    {
        const int e0 = blockIdx.x * 512 + tid;
        const int d0 = ei[NEDGES + e0];
        const int d1 = ei[NEDGES + e0 + 256];
        atomicAdd(&deg[d0], 1);
        atomicAdd(&deg[d1], 1);
    }

    {
        const fvec4* src = (const fvec4*)(x + (size_t)n_base * INDIM);
        fvec4* dst = (fvec4*)&xs[0][0];
        #pragma unroll
        for (int i = 0; i < 4; ++i) dst[tid + 256 * i] = src[tid + 256 * i];
    }
    {
        const fvec4* src = (const fvec4*)W_lin;
        fvec4* dst = (fvec4*)&Ws[0][0];
        #pragma unroll
        for (int i = 0; i < 16; ++i) dst[tid + 256 * i] = src[tid + 256 * i];
    }
    __syncthreads();

    const int cq = tid & 31;
    const int nq = tid >> 5;
    const int c0 = cq * 4;
    const int n0 = nq * 4;

    fvec4 acc[4];

    auto mmtile = [&]() {
        #pragma unroll
        for (int i = 0; i < 4; ++i) { acc[i][0] = 0.f; acc[i][1] = 0.f; acc[i][2] = 0.f; acc[i][3] = 0.f; }
        #pragma unroll 4
        for (int k = 0; k < INDIM; k += 4) {
            fvec4 w0 = *(const fvec4*)&Ws[k + 0][c0];
            fvec4 w1 = *(const fvec4*)&Ws[k + 1][c0];
            fvec4 w2 = *(const fvec4*)&Ws[k + 2][c0];
            fvec4 w3 = *(const fvec4*)&Ws[k + 3][c0];
            #pragma unroll
            for (int i = 0; i < 4; ++i) {
                fvec4 xv = *(const fvec4*)&xs[n0 + i][k];
                acc[i] += xv[0] * w0;
                acc[i] += xv[1] * w1;
                acc[i] += xv[2] * w2;
                acc[i] += xv[3] * w3;
            }
        }
    };

    // ---- phase 1: h (bf16) + alphas ----
    mmtile();
    #pragma unroll
    for (int i = 0; i < 4; ++i) {
        const int n = n_base + n0 + i;
        usvec4 hb;
        #pragma unroll
        for (int j = 0; j < 4; ++j) hb[j] = f2bf_rne(acc[i][j]);
        *(usvec4*)&h16[(size_t)n * HC + c0] = hb;
    }
    {
        float al0 = att_l[c0], al1 = att_l[c0 + 1], al2 = att_l[c0 + 2], al3 = att_l[c0 + 3];
        float ar0 = att_r[c0], ar1 = att_r[c0 + 1], ar2 = att_r[c0 + 2], ar3 = att_r[c0 + 3];
        float pl[4], pr[4];
        #pragma unroll
        for (int i = 0; i < 4; ++i) {
            pl[i] = acc[i][0] * al0 + acc[i][1] * al1 + acc[i][2] * al2 + acc[i][3] * al3;
            pr[i] = acc[i][0] * ar0 + acc[i][1] * ar1 + acc[i][2] * ar2 + acc[i][3] * ar3;
        }
        #pragma unroll
        for (int i = 0; i < 4; ++i) {
            pl[i] += __shfl_xor(pl[i], 1); pl[i] += __shfl_xor(pl[i], 2);
            pr[i] += __shfl_xor(pr[i], 1); pr[i] += __shfl_xor(pr[i], 2);
        }
        if ((cq & 3) == 0) {
            const int head = cq >> 2;
            #pragma unroll
            for (int i = 0; i < 4; ++i) {
                const int n = n_base + n0 + i;
                alpha_l[(size_t)n * NH + head] = pl[i];
                alpha_r[(size_t)n * NH + head] = pr[i];
            }
        }
    }

    // ---- phase 2: resid = x @ W_res ----
    __syncthreads();
    {
        const fvec4* src = (const fvec4*)W_res;
        fvec4* dst = (fvec4*)&Ws[0][0];
        #pragma unroll
        for (int i = 0; i < 16; ++i) dst[tid + 256 * i] = src[tid + 256 * i];
    }
    __syncthreads();
    mmtile();
    #pragma unroll
    for (int i = 0; i < 4; ++i) {
        const int n = n_base + n0 + i;
        *(fvec4*)&resid[(size_t)n * HC + c0] = acc[i];
    }
}

// ---------------------------------------------------------------------------
// CSR build: two-level scan (98 blocks -> 98 partials -> fixup) + scatter
// ---------------------------------------------------------------------------
__global__ __launch_bounds__(1024) void k_scan1(const int* __restrict__ deg,
                                                int* __restrict__ row_start,
                                                int* __restrict__ partials)
{
    __shared__ int sh[1024];
    const int t = threadIdx.x;
    const int i = blockIdx.x * 1024 + t;
    const int v = (i < NNODES) ? deg[i] : 0;
    sh[t] = v;
    __syncthreads();
    #pragma unroll
    for (int off = 1; off < 1024; off <<= 1) {
        int u = (t >= off) ? sh[t - off] : 0;
        __syncthreads();
        sh[t] += u;
        __syncthreads();
    }
    if (i < NNODES) row_start[i] = sh[t] - v;       // block-local exclusive
    if (t == 1023) partials[blockIdx.x] = sh[1023]; // block total
}

__global__ __launch_bounds__(128) void k_scan2(int* __restrict__ partials)
{
    __shared__ int sh[128];
    const int t = threadIdx.x;
    const int v = (t < NPART) ? partials[t] : 0;
    sh[t] = v;
    __syncthreads();
    #pragma unroll
    for (int off = 1; off < 128; off <<= 1) {
        int u = (t >= off) ? sh[t - off] : 0;
        __syncthreads();
        sh[t] += u;
        __syncthreads();
    }
    if (t < NPART) partials[t] = sh[t] - v;         // exclusive offsets
    if (t == 127) partials[NPART] = sh[127];        // grand total (=NEDGES)
}

__global__ __launch_bounds__(1024) void k_scan3(int* __restrict__ row_start,
                                                const int* __restrict__ partials)
{
    const int i = blockIdx.x * 1024 + threadIdx.x;
    if (i < NNODES) row_start[i] += partials[blockIdx.x];
    if (i == NNODES - 1) row_start[NNODES] = partials[NPART];
}

__global__ __launch_bounds__(256) void k_scatter(const int* __restrict__ ei,
                                                 const int* __restrict__ row_start,
                                                 int* __restrict__ cursor,
                                                 int* __restrict__ csr_src)
{
    const int e = blockIdx.x * 256 + threadIdx.x;
    if (e >= NEDGES) return;
    const int src = ei[e];
    const int dst = ei[NEDGES + e];
    const int pos = row_start[dst] + atomicAdd(&cursor[dst], 1);
    csr_src[pos] = src;
}

// ---------------------------------------------------------------------------
// Kernel C: one wave per dst node, single pass:
//   acc += w * h[src],  ssum += w,  w = exp(leaky(alpha_l[src]+alpha_r[n]))
// then out = elu(acc/ssum) + resid (resid already in d_out). No atomics.
// Lane l owns channels {2l, 2l+1}; head = l>>3.
// ---------------------------------------------------------------------------
__global__ __launch_bounds__(256) void k_msg(
    const int* __restrict__ row_start,
    const int* __restrict__ csr_src,
    const float* __restrict__ alpha_l,
    const float* __restrict__ alpha_r,
    const unsigned short* __restrict__ h16,
    float* __restrict__ out)
{
    const int n = blockIdx.x * 4 + (threadIdx.x >> 6);
    if (n >= NNODES) return;
    const int lane = threadIdx.x & 63;
    const int beg = row_start[n];
    const int end = row_start[n + 1];

    const int hd = lane >> 3;
    const float ar = alpha_r[(size_t)n * NH + hd];

    float ssum = 0.f, acc0 = 0.f, acc1 = 0.f;
    int src_n = (beg < end) ? csr_src[beg] : 0;
    for (int p = beg; p < end; ++p) {
        const int src = src_n;
        if (p + 1 < end) src_n = csr_src[p + 1];
        float a = alpha_l[(size_t)src * NH + hd] + ar;
        a = a > 0.f ? a : LEAKY * a;
        const float w = __expf(a);
        const uint32_t hv = *(const uint32_t*)&h16[(size_t)src * HC + 2 * lane];
        ssum += w;
        acc0 += w * __builtin_bit_cast(float, (hv & 0xFFFFu) << 16);
        acc1 += w * __builtin_bit_cast(float, hv & 0xFFFF0000u);
    }

    const float inv = 1.f / (ssum + SM_EPS);
    const float a0 = acc0 * inv;
    const float a1 = acc1 * inv;

    const fvec2 r = *(const fvec2*)&out[(size_t)n * HC + 2 * lane];
    fvec2 o;
    o[0] = (a0 > 0.f ? a0 : expm1f(a0)) + r[0];
    o[1] = (a1 > 0.f ? a1 : expm1f(a1)) + r[1];
    *(fvec2*)&out[(size_t)n * HC + 2 * lane] = o;
}

extern "C" void kernel_launch(void* const* d_in, const int* in_sizes, int n_in,
                              void* d_out, int out_size, void* d_ws, size_t ws_size,
                              hipStream_t stream)
{
    const float* x     = (const float*)d_in[0];
    const int*   ei    = (const int*)d_in[1];
    const float* W_lin = (const float*)d_in[2];
    const float* att_l = (const float*)d_in[3];
    const float* att_r = (const float*)d_in[4];
    const float* W_res = (const float*)d_in[5];
    float* out = (float*)d_out;

    // workspace layout
    unsigned short* h16 = (unsigned short*)d_ws;              // N*128 ushorts
    float* alpha_l  = (float*)(h16 + (size_t)NNODES * HC);    // N*8
    float* alpha_r  = alpha_l + (size_t)NNODES * NH;          // N*8
    int*   deg      = (int*)(alpha_r + (size_t)NNODES * NH);  // N
    int*   cursor   = deg + NNODES;                           // N
    int*   row_start= cursor + NNODES;                        // N+1
    int*   partials = row_start + NNODES + 1;                 // NPART+1
    int*   csr_src  = partials + NPART + 1;                   // E

    // zero deg + cursor (adjacent) every launch
    hipMemsetAsync(deg, 0, 2 * (size_t)NNODES * sizeof(int), stream);

    k_gemm<<<NNODES / NB, 256, 0, stream>>>(x, W_lin, W_res, att_l, att_r, ei,
                                            h16, alpha_l, alpha_r, out, deg);
    k_scan1<<<NPART, 1024, 0, stream>>>(deg, row_start, partials);
    k_scan2<<<1, 128, 0, stream>>>(partials);
    k_scan3<<<NPART, 1024, 0, stream>>>(row_start, partials);
    k_scatter<<<(NEDGES + 255) / 256, 256, 0, stream>>>(ei, row_start, cursor, csr_src);
    k_msg<<<(NNODES + 3) / 4, 256, 0, stream>>>(row_start, csr_src, alpha_l, alpha_r, h16, out);
}

// Round 5
// 331.504 us; speedup vs baseline: 4.4595x; 1.0387x over previous
//
#include <hip/hip_runtime.h>
#include <cstdint>
#include <cstddef>

typedef __attribute__((ext_vector_type(4))) float fvec4;
typedef __attribute__((ext_vector_type(2))) float fvec2;
typedef __attribute__((ext_vector_type(8))) short bf8;            // 8 bf16 = 4 VGPR MFMA frag
typedef __attribute__((ext_vector_type(8))) unsigned short usvec8;
typedef __attribute__((ext_vector_type(4))) float f32x4;

#define NNODES 100000
#define NEDGES 1600000
#define INDIM  128
#define HC     128
#define NH     8
#define LEAKY  0.2f
#define SM_EPS 1e-16f
#define NPART  98    // ceil(100000/1024)
#define BM     64    // nodes per block in k_gemm
#define GEMM_BLOCKS ((NNODES + BM - 1) / BM)   // 1563

__device__ __forceinline__ unsigned short f2bf_rne(float f) {
    uint32_t u = __builtin_bit_cast(uint32_t, f);
    u += 0x7FFFu + ((u >> 16) & 1u);
    return (unsigned short)(u >> 16);
}
__device__ __forceinline__ float bf2f(uint32_t lo16) {
    return __builtin_bit_cast(float, lo16 << 16);
}

// ---------------------------------------------------------------------------
// k_wt: W_lin,W_res (f32 [K=128][N=128]) -> wt_g (bf16, transposed [n=256][k=128],
// pre-swizzled: 16B slot index ^= (n&7)). 16 blocks x 256 threads; thread =
// (n, k8) handles 8 k-values of one output row.
// ---------------------------------------------------------------------------
__global__ __launch_bounds__(256) void k_wt(
    const float* __restrict__ W_lin,
    const float* __restrict__ W_res,
    unsigned short* __restrict__ wt_g)
{
    const int idx = blockIdx.x * 256 + threadIdx.x;   // 0..4095
    const int n  = idx >> 4;                          // 0..255
    const int k8 = idx & 15;
    const float* src = (n < 128) ? W_lin : W_res;
    const int col = n & 127;
    usvec8 o;
    #pragma unroll
    for (int j = 0; j < 8; ++j)
        o[j] = f2bf_rne(src[(size_t)(k8 * 8 + j) * HC + col]);
    const int sw = k8 ^ (n & 7);
    *(usvec8*)&wt_g[(size_t)n * INDIM + sw * 8] = o;
}

// ---------------------------------------------------------------------------
// k_gemm (MFMA): per block 64 nodes x 256 cols (h | resid), K=128.
// 4 waves; wave w owns rows [16w,16w+16). 16 col-tiles of 16, 4 k-steps of 32.
// LDS: wt 64KB (pre-swizzled copy) + xs 16KB (f32->bf16, swizzled) = 80KB.
// Frag layouts (gfx950 16x16x32 bf16): A: lane l = row l&15, k=8*(l>>4)+i;
// B: col l&15, k=8*(l>>4)+i; D: col=l&15, row=4*(l>>4)+reg  [m89/m91].
// Fused: dst-degree histogram (4 edges/thread).
// ---------------------------------------------------------------------------
__global__ __launch_bounds__(256) void k_gemm(
    const float* __restrict__ x,
    const unsigned short* __restrict__ wt_g,
    const int*   __restrict__ ei,
    unsigned short* __restrict__ h16,
    unsigned short* __restrict__ resid16,
    int* __restrict__ deg)
{
    __shared__ unsigned short wt[256 * INDIM];  // 64 KB
    __shared__ unsigned short xs[BM * INDIM];   // 16 KB

    const int tid = threadIdx.x;
    const size_t nbase = (size_t)blockIdx.x * BM;

    // fused histogram: 1563*256*4 >= 1.6M
    #pragma unroll
    for (int i = 0; i < 4; ++i) {
        const int e = blockIdx.x * 256 + tid + i * (GEMM_BLOCKS * 256);
        if (e < NEDGES) atomicAdd(&deg[ei[NEDGES + e]], 1);
    }

    // stage wt (linear copy of pre-swizzled bf16)
    {
        const fvec4* s = (const fvec4*)wt_g;
        fvec4* d = (fvec4*)wt;
        #pragma unroll
        for (int i = 0; i < 16; ++i) d[tid + 256 * i] = s[tid + 256 * i];
    }
    // stage xs: thread = (row r0, quarter kq); convert f32->bf16, swizzled store
    {
        const int r0 = tid >> 2;
        const int kq = (tid & 3) * 32;
        const bool valid = (nbase + r0) < NNODES;
        const float* xr = x + (nbase + r0) * INDIM + kq;
        #pragma unroll
        for (int j2 = 0; j2 < 4; ++j2) {
            usvec8 o;
            if (valid) {
                fvec4 p0 = *(const fvec4*)(xr + j2 * 8);
                fvec4 p1 = *(const fvec4*)(xr + j2 * 8 + 4);
                #pragma unroll
                for (int j = 0; j < 4; ++j) { o[j] = f2bf_rne(p0[j]); o[4 + j] = f2bf_rne(p1[j]); }
            } else {
                #pragma unroll
                for (int j = 0; j < 8; ++j) o[j] = 0;
            }
            const int slot = (kq >> 3) + j2;            // 0..15
            const int sw = slot ^ (r0 & 7);
            *(usvec8*)&xs[r0 * INDIM + sw * 8] = o;
        }
    }
    __syncthreads();

    const int wid  = tid >> 6;
    const int lane = tid & 63;
    const int r = lane & 15;
    const int g = lane >> 4;
    const int arow = wid * 16 + r;

    // A fragments (reused across all 16 col-tiles)
    bf8 a[4];
    #pragma unroll
    for (int kk = 0; kk < 4; ++kk) {
        const int sw = (kk * 4 + g) ^ (arow & 7);
        a[kk] = *(const bf8*)&xs[arow * INDIM + sw * 8];
    }

    f32x4 acc[16];
    #pragma unroll
    for (int t = 0; t < 16; ++t) acc[t] = (f32x4){0.f, 0.f, 0.f, 0.f};

    #pragma unroll
    for (int kk = 0; kk < 4; ++kk) {
        #pragma unroll
        for (int t = 0; t < 16; ++t) {
            const int n = t * 16 + r;
            const int sw = (kk * 4 + g) ^ (n & 7);
            const bf8 b = *(const bf8*)&wt[n * INDIM + sw * 8];
            acc[t] = __builtin_amdgcn_mfma_f32_16x16x32_bf16(a[kk], b, acc[t], 0, 0, 0);
        }
    }

    // epilogue: D[row=4g+ri][col=t*16+r]
    #pragma unroll
    for (int t = 0; t < 16; ++t) {
        #pragma unroll
        for (int ri = 0; ri < 4; ++ri) {
            const size_t node = nbase + wid * 16 + 4 * g + ri;
            if (node < NNODES) {
                if (t < 8) h16[node * HC + t * 16 + r]              = f2bf_rne(acc[t][ri]);
                else       resid16[node * HC + (t - 8) * 16 + r]    = f2bf_rne(acc[t][ri]);
            }
        }
    }
}

// ---------------------------------------------------------------------------
// k_alpha: per node, alpha_{l,r}[n][h] = sum_c h[n][c]*att_{l,r}[c].
// One wave per node; lane owns cols {2l,2l+1}; head = lane>>3.
// ---------------------------------------------------------------------------
__global__ __launch_bounds__(256) void k_alpha(
    const unsigned short* __restrict__ h16,
    const float* __restrict__ att_l,
    const float* __restrict__ att_r,
    float* __restrict__ alpha_l,
    float* __restrict__ alpha_r)
{
    const int n = blockIdx.x * 4 + (threadIdx.x >> 6);
    if (n >= NNODES) return;
    const int lane = threadIdx.x & 63;
    const uint32_t hv = *(const uint32_t*)&h16[(size_t)n * HC + 2 * lane];
    const float h0 = bf2f(hv & 0xFFFFu);
    const float h1 = bf2f(hv >> 16);
    float pl = h0 * att_l[2 * lane] + h1 * att_l[2 * lane + 1];
    float pr = h0 * att_r[2 * lane] + h1 * att_r[2 * lane + 1];
    pl += __shfl_xor(pl, 1); pl += __shfl_xor(pl, 2); pl += __shfl_xor(pl, 4);
    pr += __shfl_xor(pr, 1); pr += __shfl_xor(pr, 2); pr += __shfl_xor(pr, 4);
    if ((lane & 7) == 0) {
        alpha_l[(size_t)n * NH + (lane >> 3)] = pl;
        alpha_r[(size_t)n * NH + (lane >> 3)] = pr;
    }
}

// ---------------------------------------------------------------------------
// CSR build: two-level scan + scatter
// ---------------------------------------------------------------------------
__global__ __launch_bounds__(1024) void k_scan1(const int* __restrict__ deg,
                                                int* __restrict__ row_start,
                                                int* __restrict__ partials)
{
    __shared__ int sh[1024];
    const int t = threadIdx.x;
    const int i = blockIdx.x * 1024 + t;
    const int v = (i < NNODES) ? deg[i] : 0;
    sh[t] = v;
    __syncthreads();
    #pragma unroll
    for (int off = 1; off < 1024; off <<= 1) {
        int u = (t >= off) ? sh[t - off] : 0;
        __syncthreads();
        sh[t] += u;
        __syncthreads();
    }
    if (i < NNODES) row_start[i] = sh[t] - v;
    if (t == 1023) partials[blockIdx.x] = sh[1023];
}

__global__ __launch_bounds__(128) void k_scan2(int* __restrict__ partials)
{
    __shared__ int sh[128];
    const int t = threadIdx.x;
    const int v = (t < NPART) ? partials[t] : 0;
    sh[t] = v;
    __syncthreads();
    #pragma unroll
    for (int off = 1; off < 128; off <<= 1) {
        int u = (t >= off) ? sh[t - off] : 0;
        __syncthreads();
        sh[t] += u;
        __syncthreads();
    }
    if (t < NPART) partials[t] = sh[t] - v;
    if (t == 127) partials[NPART] = sh[127];
}

__global__ __launch_bounds__(1024) void k_scan3(int* __restrict__ row_start,
                                                const int* __restrict__ partials)
{
    const int i = blockIdx.x * 1024 + threadIdx.x;
    if (i < NNODES) row_start[i] += partials[blockIdx.x];
    if (i == NNODES - 1) row_start[NNODES] = partials[NPART];
}

__global__ __launch_bounds__(256) void k_scatter(const int* __restrict__ ei,
                                                 const int* __restrict__ row_start,
                                                 int* __restrict__ cursor,
                                                 int* __restrict__ csr_src)
{
    const int e = blockIdx.x * 256 + threadIdx.x;
    if (e >= NEDGES) return;
    const int src = ei[e];
    const int dst = ei[NEDGES + e];
    const int pos = row_start[dst] + atomicAdd(&cursor[dst], 1);
    csr_src[pos] = src;
}

// ---------------------------------------------------------------------------
// k_msg: one wave per dst node, single pass:
//   acc += w * h[src], ssum += w, w = exp(leaky(alpha_l[src]+alpha_r[n]))
// out = elu(acc/ssum) + resid16. Lane l owns cols {2l,2l+1}; head = l>>3.
// ---------------------------------------------------------------------------
__global__ __launch_bounds__(256) void k_msg(
    const int* __restrict__ row_start,
    const int* __restrict__ csr_src,
    const float* __restrict__ alpha_l,
    const float* __restrict__ alpha_r,
    const unsigned short* __restrict__ h16,
    const unsigned short* __restrict__ resid16,
    float* __restrict__ out)
{
    const int n = blockIdx.x * 4 + (threadIdx.x >> 6);
    if (n >= NNODES) return;
    const int lane = threadIdx.x & 63;
    const int beg = row_start[n];
    const int end = row_start[n + 1];

    const int hd = lane >> 3;
    const float ar = alpha_r[(size_t)n * NH + hd];

    float ssum = 0.f, acc0 = 0.f, acc1 = 0.f;
    int src_n = (beg < end) ? csr_src[beg] : 0;
    for (int p = beg; p < end; ++p) {
        const int src = src_n;
        if (p + 1 < end) src_n = csr_src[p + 1];
        float a = alpha_l[(size_t)src * NH + hd] + ar;
        a = a > 0.f ? a : LEAKY * a;
        const float w = __expf(a);
        const uint32_t hv = *(const uint32_t*)&h16[(size_t)src * HC + 2 * lane];
        ssum += w;
        acc0 += w * bf2f(hv & 0xFFFFu);
        acc1 += w * bf2f(hv >> 16);
    }

    const float inv = 1.f / (ssum + SM_EPS);
    const float a0 = acc0 * inv;
    const float a1 = acc1 * inv;

    const uint32_t rv = *(const uint32_t*)&resid16[(size_t)n * HC + 2 * lane];
    fvec2 o;
    o[0] = (a0 > 0.f ? a0 : expm1f(a0)) + bf2f(rv & 0xFFFFu);
    o[1] = (a1 > 0.f ? a1 : expm1f(a1)) + bf2f(rv >> 16);
    *(fvec2*)&out[(size_t)n * HC + 2 * lane] = o;
}

extern "C" void kernel_launch(void* const* d_in, const int* in_sizes, int n_in,
                              void* d_out, int out_size, void* d_ws, size_t ws_size,
                              hipStream_t stream)
{
    const float* x     = (const float*)d_in[0];
    const int*   ei    = (const int*)d_in[1];
    const float* W_lin = (const float*)d_in[2];
    const float* att_l = (const float*)d_in[3];
    const float* att_r = (const float*)d_in[4];
    const float* W_res = (const float*)d_in[5];
    float* out = (float*)d_out;

    // workspace layout
    unsigned short* wt_g    = (unsigned short*)d_ws;              // 256*128
    unsigned short* h16     = wt_g + 256 * INDIM;                 // N*128
    unsigned short* resid16 = h16 + (size_t)NNODES * HC;          // N*128
    float* alpha_l  = (float*)(resid16 + (size_t)NNODES * HC);    // N*8
    float* alpha_r  = alpha_l + (size_t)NNODES * NH;              // N*8
    int*   deg      = (int*)(alpha_r + (size_t)NNODES * NH);      // N
    int*   cursor   = deg + NNODES;                               // N
    int*   row_start= cursor + NNODES;                            // N+1
    int*   partials = row_start + NNODES + 1;                     // NPART+1
    int*   csr_src  = partials + NPART + 1;                       // E

    hipMemsetAsync(deg, 0, 2 * (size_t)NNODES * sizeof(int), stream);

    k_wt<<<16, 256, 0, stream>>>(W_lin, W_res, wt_g);
    k_gemm<<<GEMM_BLOCKS, 256, 0, stream>>>(x, wt_g, ei, h16, resid16, deg);
    k_alpha<<<(NNODES + 3) / 4, 256, 0, stream>>>(h16, att_l, att_r, alpha_l, alpha_r);
    k_scan1<<<NPART, 1024, 0, stream>>>(deg, row_start, partials);
    k_scan2<<<1, 128, 0, stream>>>(partials);
    k_scan3<<<NPART, 1024, 0, stream>>>(row_start, partials);
    k_scatter<<<(NEDGES + 255) / 256, 256, 0, stream>>>(ei, row_start, cursor, csr_src);
    k_msg<<<(NNODES + 3) / 4, 256, 0, stream>>>(row_start, csr_src, alpha_l, alpha_r, h16, resid16, out);
}

// Round 6
// 286.750 us; speedup vs baseline: 5.1555x; 1.1561x over previous
//
#include <hip/hip_runtime.h>
#include <cstdint>
#include <cstddef>

typedef __attribute__((ext_vector_type(4))) float fvec4;
typedef __attribute__((ext_vector_type(2))) float fvec2;
typedef __attribute__((ext_vector_type(8))) short bf8;            // 8 bf16 = 4 VGPR MFMA frag
typedef __attribute__((ext_vector_type(8))) unsigned short usvec8;
typedef __attribute__((ext_vector_type(4))) float f32x4;

#define NNODES 100000
#define NEDGES 1600000
#define INDIM  128
#define HC     128
#define NH     8
#define LEAKY  0.2f
#define SM_EPS 1e-16f
#define NPART  98    // ceil(100000/1024)
#define BM     64    // nodes per block in k_gemm
#define GEMM_BLOCKS ((NNODES + BM - 1) / BM)   // 1563
#define WROWS  272   // 256 W cols + 8 wa_l + 8 wa_r

__device__ __forceinline__ unsigned short f2bf_rne(float f) {
    uint32_t u = __builtin_bit_cast(uint32_t, f);
    u += 0x7FFFu + ((u >> 16) & 1u);
    return (unsigned short)(u >> 16);
}
__device__ __forceinline__ float bf2f(uint32_t lo16) {
    return __builtin_bit_cast(float, lo16 << 16);
}

// ---------------------------------------------------------------------------
// k_wt: build wt_g (bf16):
//   rows 0..255:  W_lin|W_res transposed [n][k], pre-swizzled 16B slots (^= n&7)
//   rows 256..263: wa_l[k,hd] = sum_{c in head hd} W_lin[k,c]*att_l[c]  (no swz)
//   rows 264..271: wa_r likewise. 17 blocks x 256 threads; thread = (n, k8).
// ---------------------------------------------------------------------------
__global__ __launch_bounds__(256) void k_wt(
    const float* __restrict__ W_lin,
    const float* __restrict__ W_res,
    const float* __restrict__ att_l,
    const float* __restrict__ att_r,
    unsigned short* __restrict__ wt_g)
{
    const int idx = blockIdx.x * 256 + threadIdx.x;   // 0..4351
    if (idx >= WROWS * 16) return;
    const int n  = idx >> 4;                          // 0..271
    const int k8 = idx & 15;
    usvec8 o;
    if (n < 256) {
        const float* src = (n < 128) ? W_lin : W_res;
        const int col = n & 127;
        #pragma unroll
        for (int j = 0; j < 8; ++j)
            o[j] = f2bf_rne(src[(size_t)(k8 * 8 + j) * HC + col]);
        const int sw = k8 ^ (n & 7);
        *(usvec8*)&wt_g[(size_t)n * INDIM + sw * 8] = o;
    } else {
        const int hd = (n - 256) & 7;
        const float* att = (n < 264) ? att_l : att_r;
        #pragma unroll
        for (int j = 0; j < 8; ++j) {
            const int k = k8 * 8 + j;
            float s = 0.f;
            #pragma unroll
            for (int c = 0; c < 16; ++c)
                s += W_lin[(size_t)k * HC + 16 * hd + c] * att[16 * hd + c];
            o[j] = f2bf_rne(s);
        }
        *(usvec8*)&wt_g[(size_t)n * INDIM + k8 * 8] = o;
    }
}

// ---------------------------------------------------------------------------
// k_gemm (MFMA): per block 64 nodes x 272 cols (h | resid | alphas), K=128.
// 4 waves; wave w rows [16w,16w+16). 17 col-tiles of 16, 4 k-steps of 32.
// LDS: wt 64KB (tiles 0..15) + xs 16KB = 80KB -> 2 blocks/CU; tile 16 (alphas)
// B-frags read straight from global (L2-hot 4KB).
// Epilogue: stage D in reused wt LDS (XOR swizzle), coalesced wide stores.
// Fused: dst-degree histogram (4 edges/thread).
// ---------------------------------------------------------------------------
__global__ __launch_bounds__(256) void k_gemm(
    const float* __restrict__ x,
    const unsigned short* __restrict__ wt_g,
    const int*   __restrict__ ei,
    unsigned short* __restrict__ h16,
    unsigned short* __restrict__ resid16,
    float* __restrict__ alpha_l,
    float* __restrict__ alpha_r,
    int* __restrict__ deg)
{
    __shared__ unsigned short wt[256 * INDIM];  // 64 KB
    __shared__ unsigned short xs[BM * INDIM];   // 16 KB

    const int tid = threadIdx.x;
    const size_t nbase = (size_t)blockIdx.x * BM;

    // fused histogram: 1563*256*4 >= 1.6M
    #pragma unroll
    for (int i = 0; i < 4; ++i) {
        const int e = blockIdx.x * 256 + tid + i * (GEMM_BLOCKS * 256);
        if (e < NEDGES) atomicAdd(&deg[ei[NEDGES + e]], 1);
    }

    // stage wt rows 0..255 (linear copy of pre-swizzled bf16)
    {
        const fvec4* s = (const fvec4*)wt_g;
        fvec4* d = (fvec4*)wt;
        #pragma unroll
        for (int i = 0; i < 16; ++i) d[tid + 256 * i] = s[tid + 256 * i];
    }
    // stage xs: thread = (row r0, quarter kq); f32->bf16, swizzled store
    {
        const int r0 = tid >> 2;
        const int kq = (tid & 3) * 32;
        const bool valid = (nbase + r0) < NNODES;
        const float* xr = x + (nbase + r0) * INDIM + kq;
        #pragma unroll
        for (int j2 = 0; j2 < 4; ++j2) {
            usvec8 o;
            if (valid) {
                fvec4 p0 = *(const fvec4*)(xr + j2 * 8);
                fvec4 p1 = *(const fvec4*)(xr + j2 * 8 + 4);
                #pragma unroll
                for (int j = 0; j < 4; ++j) { o[j] = f2bf_rne(p0[j]); o[4 + j] = f2bf_rne(p1[j]); }
            } else {
                #pragma unroll
                for (int j = 0; j < 8; ++j) o[j] = 0;
            }
            const int slot = (kq >> 3) + j2;            // 0..15
            const int sw = slot ^ (r0 & 7);
            *(usvec8*)&xs[r0 * INDIM + sw * 8] = o;
        }
    }

    const int wid  = tid >> 6;
    const int lane = tid & 63;
    const int r = lane & 15;
    const int g = lane >> 4;
    const int arow = wid * 16 + r;

    // alpha-tile B fragments straight from global (issue early)
    bf8 wa[4];
    #pragma unroll
    for (int kk = 0; kk < 4; ++kk)
        wa[kk] = *(const bf8*)&wt_g[(size_t)(256 + r) * INDIM + kk * 32 + g * 8];

    __syncthreads();

    // A fragments (reused across all 17 col-tiles)
    bf8 a[4];
    #pragma unroll
    for (int kk = 0; kk < 4; ++kk) {
        const int sw = (kk * 4 + g) ^ (arow & 7);
        a[kk] = *(const bf8*)&xs[arow * INDIM + sw * 8];
    }

    f32x4 acc[17];
    #pragma unroll
    for (int t = 0; t < 17; ++t) acc[t] = (f32x4){0.f, 0.f, 0.f, 0.f};

    #pragma unroll
    for (int kk = 0; kk < 4; ++kk) {
        #pragma unroll
        for (int t = 0; t < 16; ++t) {
            const int n = t * 16 + r;
            const int sw = (kk * 4 + g) ^ (n & 7);
            const bf8 b = *(const bf8*)&wt[n * INDIM + sw * 8];
            acc[t] = __builtin_amdgcn_mfma_f32_16x16x32_bf16(a[kk], b, acc[t], 0, 0, 0);
        }
        acc[16] = __builtin_amdgcn_mfma_f32_16x16x32_bf16(a[kk], wa[kk], acc[16], 0, 0, 0);
    }

    // alphas: D[row=4g+ri][col=r]; r<8 -> alpha_l head r, r>=8 -> alpha_r
    #pragma unroll
    for (int ri = 0; ri < 4; ++ri) {
        const size_t node = nbase + wid * 16 + 4 * g + ri;
        if (node < NNODES) {
            if (r < 8) alpha_l[node * NH + r]       = acc[16][ri];
            else       alpha_r[node * NH + (r - 8)] = acc[16][ri];
        }
    }

    // epilogue: stage D into reused wt LDS (per-wave 8KB), then wide stores
    __syncthreads();   // all waves done reading wt
    unsigned short* st = wt + wid * 4096;   // 16 rows x 256 shorts
    #pragma unroll
    for (int t = 0; t < 16; ++t) {
        #pragma unroll
        for (int ri = 0; ri < 4; ++ri) {
            const int row = 4 * g + ri;
            st[row * 256 + ((t ^ (row & 7)) << 4) + r] = f2bf_rne(acc[t][ri]);
        }
    }
    __syncthreads();   // order LDS writes before cross-lane reads

    {
        const int li = lane & 15;
        const int t  = li >> 1;
        const int half = li & 1;
        #pragma unroll
        for (int it = 0; it < 4; ++it) {
            const int row = it * 4 + (lane >> 4);
            const size_t node = nbase + wid * 16 + row;
            const usvec8 vh = *(const usvec8*)&st[row * 256 + ((t ^ (row & 7)) << 4) + half * 8];
            const usvec8 vr = *(const usvec8*)&st[row * 256 + (((8 + t) ^ (row & 7)) << 4) + half * 8];
            if (node < NNODES) {
                *(usvec8*)&h16[node * HC + li * 8]     = vh;
                *(usvec8*)&resid16[node * HC + li * 8] = vr;
            }
        }
    }
}

// ---------------------------------------------------------------------------
// CSR build: two-level scan + scatter
// ---------------------------------------------------------------------------
__global__ __launch_bounds__(1024) void k_scan1(const int* __restrict__ deg,
                                                int* __restrict__ row_start,
                                                int* __restrict__ partials)
{
    __shared__ int sh[1024];
    const int t = threadIdx.x;
    const int i = blockIdx.x * 1024 + t;
    const int v = (i < NNODES) ? deg[i] : 0;
    sh[t] = v;
    __syncthreads();
    #pragma unroll
    for (int off = 1; off < 1024; off <<= 1) {
        int u = (t >= off) ? sh[t - off] : 0;
        __syncthreads();
        sh[t] += u;
        __syncthreads();
    }
    if (i < NNODES) row_start[i] = sh[t] - v;
    if (t == 1023) partials[blockIdx.x] = sh[1023];
}

__global__ __launch_bounds__(128) void k_scan2(int* __restrict__ partials)
{
    __shared__ int sh[128];
    const int t = threadIdx.x;
    const int v = (t < NPART) ? partials[t] : 0;
    sh[t] = v;
    __syncthreads();
    #pragma unroll
    for (int off = 1; off < 128; off <<= 1) {
        int u = (t >= off) ? sh[t - off] : 0;
        __syncthreads();
        sh[t] += u;
        __syncthreads();
    }
    if (t < NPART) partials[t] = sh[t] - v;
    if (t == 127) partials[NPART] = sh[127];
}

__global__ __launch_bounds__(1024) void k_scan3(int* __restrict__ row_start,
                                                const int* __restrict__ partials)
{
    const int i = blockIdx.x * 1024 + threadIdx.x;
    if (i < NNODES) row_start[i] += partials[blockIdx.x];
    if (i == NNODES - 1) row_start[NNODES] = partials[NPART];
}

__global__ __launch_bounds__(256) void k_scatter(const int* __restrict__ ei,
                                                 const int* __restrict__ row_start,
                                                 int* __restrict__ cursor,
                                                 int* __restrict__ csr_src)
{
    const int e = blockIdx.x * 256 + threadIdx.x;
    if (e >= NEDGES) return;
    const int src = ei[e];
    const int dst = ei[NEDGES + e];
    const int pos = row_start[dst] + atomicAdd(&cursor[dst], 1);
    csr_src[pos] = src;
}

// ---------------------------------------------------------------------------
// k_msg: one wave per dst node, 4 edges per iteration.
// lane = (sub = lane>>4 -> edge subgroup, li = lane&15 -> channels [8li,8li+8),
// head = li>>1). Single pass: acc += w*h[src], ssum += w; xor-reduce across
// subgroups; lanes sub==0 apply softmax-normalize + ELU + resid, wide store.
// ---------------------------------------------------------------------------
__global__ __launch_bounds__(256) void k_msg(
    const int* __restrict__ row_start,
    const int* __restrict__ csr_src,
    const float* __restrict__ alpha_l,
    const float* __restrict__ alpha_r,
    const unsigned short* __restrict__ h16,
    const unsigned short* __restrict__ resid16,
    float* __restrict__ out)
{
    const int n = blockIdx.x * 4 + (threadIdx.x >> 6);
    if (n >= NNODES) return;
    const int lane = threadIdx.x & 63;
    const int sub  = lane >> 4;
    const int li   = lane & 15;
    const int hd   = li >> 1;

    const int beg = row_start[n];
    const int end = row_start[n + 1];
    const float ar = alpha_r[(size_t)n * NH + hd];

    float ssum = 0.f;
    float acc[8];
    #pragma unroll
    for (int j = 0; j < 8; ++j) acc[j] = 0.f;

    for (int p = beg; p < end; p += 4) {
        const int q = p + sub;
        const bool valid = q < end;
        const int qc = valid ? q : (end - 1);
        const int src = csr_src[qc];
        float a = alpha_l[(size_t)src * NH + hd] + ar;
        a = a > 0.f ? a : LEAKY * a;
        const float w = valid ? __expf(a) : 0.f;
        const usvec8 hv = *(const usvec8*)&h16[(size_t)src * HC + 8 * li];
        ssum += w;
        #pragma unroll
        for (int j = 0; j < 8; ++j) acc[j] += w * bf2f((uint32_t)hv[j]);
    }

    // reduce across the 4 edge subgroups
    ssum += __shfl_xor(ssum, 16);
    ssum += __shfl_xor(ssum, 32);
    #pragma unroll
    for (int j = 0; j < 8; ++j) {
        acc[j] += __shfl_xor(acc[j], 16);
        acc[j] += __shfl_xor(acc[j], 32);
    }

    if (sub == 0) {
        const float inv = 1.f / (ssum + SM_EPS);
        const usvec8 rv = *(const usvec8*)&resid16[(size_t)n * HC + 8 * li];
        fvec4 o0, o1;
        #pragma unroll
        for (int j = 0; j < 8; ++j) {
            float v = acc[j] * inv;
            v = (v > 0.f ? v : expm1f(v)) + bf2f((uint32_t)rv[j]);
            if (j < 4) o0[j] = v; else o1[j - 4] = v;
        }
        *(fvec4*)&out[(size_t)n * HC + 8 * li]     = o0;
        *(fvec4*)&out[(size_t)n * HC + 8 * li + 4] = o1;
    }
}

extern "C" void kernel_launch(void* const* d_in, const int* in_sizes, int n_in,
                              void* d_out, int out_size, void* d_ws, size_t ws_size,
                              hipStream_t stream)
{
    const float* x     = (const float*)d_in[0];
    const int*   ei    = (const int*)d_in[1];
    const float* W_lin = (const float*)d_in[2];
    const float* att_l = (const float*)d_in[3];
    const float* att_r = (const float*)d_in[4];
    const float* W_res = (const float*)d_in[5];
    float* out = (float*)d_out;

    // workspace layout
    unsigned short* wt_g    = (unsigned short*)d_ws;              // 272*128
    unsigned short* h16     = wt_g + (size_t)WROWS * INDIM;       // N*128
    unsigned short* resid16 = h16 + (size_t)NNODES * HC;          // N*128
    float* alpha_l  = (float*)(resid16 + (size_t)NNODES * HC);    // N*8
    float* alpha_r  = alpha_l + (size_t)NNODES * NH;              // N*8
    int*   deg      = (int*)(alpha_r + (size_t)NNODES * NH);      // N
    int*   cursor   = deg + NNODES;                               // N
    int*   row_start= cursor + NNODES;                            // N+1
    int*   partials = row_start + NNODES + 1;                     // NPART+1
    int*   csr_src  = partials + NPART + 1;                       // E

    hipMemsetAsync(deg, 0, 2 * (size_t)NNODES * sizeof(int), stream);

    k_wt<<<17, 256, 0, stream>>>(W_lin, W_res, att_l, att_r, wt_g);
    k_gemm<<<GEMM_BLOCKS, 256, 0, stream>>>(x, wt_g, ei, h16, resid16,
                                            alpha_l, alpha_r, deg);
    k_scan1<<<NPART, 1024, 0, stream>>>(deg, row_start, partials);
    k_scan2<<<1, 128, 0, stream>>>(partials);
    k_scan3<<<NPART, 1024, 0, stream>>>(row_start, partials);
    k_scatter<<<(NEDGES + 255) / 256, 256, 0, stream>>>(ei, row_start, cursor, csr_src);
    k_msg<<<(NNODES + 3) / 4, 256, 0, stream>>>(row_start, csr_src, alpha_l, alpha_r,
                                                h16, resid16, out);
}